// Round 2
// baseline (2786.040 us; speedup 1.0000x reference)
//
#include <hip/hip_runtime.h>
#include <math.h>

#define N_NODES 100000
#define N_EDGES 1600000

// ---------------- degree / normalization ----------------

__global__ void k_deg_init(float* __restrict__ deg) {
    int i = blockIdx.x * blockDim.x + threadIdx.x;
    if (i < N_NODES) deg[i] = 1.0f;   // self-loop contributes 1
}

__global__ void k_deg_scatter(const int* __restrict__ dst, float* __restrict__ deg) {
    int e = blockIdx.x * blockDim.x + threadIdx.x;
    if (e < N_EDGES) atomicAdd(&deg[dst[e]], 1.0f);
}

__global__ void k_dinv(float* __restrict__ deg) {
    int i = blockIdx.x * blockDim.x + threadIdx.x;
    if (i < N_NODES) deg[i] = rsqrtf(deg[i]);   // deg >= 1 always
}

// ---------------- dense GEMM: h = in @ W  (Dout = 64) ----------------
// Block = 256 threads = 4 waves; each wave computes one node row (64 outputs).
// W staged in LDS (conflict-free: lanes read consecutive columns).

template<int DIN>
__global__ void k_gemm(const float* __restrict__ in, const float* __restrict__ W,
                       float* __restrict__ h) {
    __shared__ float sW[DIN * 64];
    int tid = threadIdx.x;
    for (int k = tid; k < DIN * 64; k += 256) sW[k] = W[k];
    __syncthreads();

    int node = blockIdx.x * 4 + (tid >> 6);
    int col  = tid & 63;
    if (node >= N_NODES) return;

    const float* __restrict__ row = in + (size_t)node * DIN;
    float acc = 0.0f;
#pragma unroll
    for (int k = 0; k < DIN; ++k)
        acc = fmaf(row[k], sW[k * 64 + col], acc);
    h[(size_t)node * 64 + col] = acc;
}

// ---------------- self-loop init: agg[i] = h[i] * dinv[i]^2 ----------------

__global__ void k_selfloop(const float* __restrict__ h, const float* __restrict__ dinv,
                           float* __restrict__ agg) {
    int i = blockIdx.x * blockDim.x + threadIdx.x;
    if (i < N_NODES * 64) {
        int node = i >> 6;
        float d = dinv[node];
        agg[i] = h[i] * d * d;
    }
}

// ---------------- edge scatter: agg[dst] += h[src] * dinv[src]*dinv[dst] ----
// 64 lanes per edge (one wave); lane = column. Coalesced 256B atomic bursts.

__global__ void k_edge_scatter(const int* __restrict__ src,
                               const int* __restrict__ dst,
                               const float* __restrict__ dinv,
                               const float* __restrict__ h,
                               float* __restrict__ agg) {
    int e = blockIdx.x * (blockDim.x >> 6) + (threadIdx.x >> 6);
    int lane = threadIdx.x & 63;
    if (e >= N_EDGES) return;
    int s = src[e];
    int d = dst[e];
    float nrm = dinv[s] * dinv[d];
    float v = h[(size_t)s * 64 + lane] * nrm;
    atomicAdd(&agg[(size_t)d * 64 + lane], v);
}

// ---------------- bias + relu (in place) ----------------

__global__ void k_bias_relu(float* __restrict__ agg, const float* __restrict__ b) {
    int i = blockIdx.x * blockDim.x + threadIdx.x;
    if (i < N_NODES * 64) {
        float v = agg[i] + b[i & 63];
        agg[i] = v > 0.0f ? v : 0.0f;
    }
}

// ---------------- log_softmax over 64 columns (one wave per node) ----------
// In-place safe: each thread reads its own element before any write.

__global__ void k_logsoftmax(const float* __restrict__ in, float* __restrict__ out) {
    int node = blockIdx.x * (blockDim.x >> 6) + (threadIdx.x >> 6);
    int lane = threadIdx.x & 63;
    if (node >= N_NODES) return;
    float v = in[(size_t)node * 64 + lane];
    float m = v;
#pragma unroll
    for (int o = 32; o; o >>= 1) m = fmaxf(m, __shfl_xor(m, o));
    float ex = expf(v - m);
    float ssum = ex;
#pragma unroll
    for (int o = 32; o; o >>= 1) ssum += __shfl_xor(ssum, o);
    out[(size_t)node * 64 + lane] = v - m - logf(ssum);
}

// ---------------- launch ----------------

extern "C" void kernel_launch(void* const* d_in, const int* in_sizes, int n_in,
                              void* d_out, int out_size, void* d_ws, size_t ws_size,
                              hipStream_t stream) {
    const float* x = (const float*)d_in[0];
    const int* ei = (const int*)d_in[1];     // harness converts integer inputs to int32
    const int* src = ei;                      // edge_index[0]
    const int* dst = ei + N_EDGES;            // edge_index[1]

    const float* W[6];
    const float* b[6];
    for (int i = 0; i < 6; ++i) {
        W[i] = (const float*)d_in[2 + 2 * i];
        b[i] = (const float*)d_in[3 + 2 * i];
    }
    float* out = (float*)d_out;

    // buffers: dinv [N] + h [N*64] in ws; agg aliases d_out (fully rewritten
    // every call -> no cross-call state).
    float* dinv = (float*)d_ws;
    float* h    = dinv + N_NODES;
    float* agg  = (float*)d_out;

    // normalization coefficients
    k_deg_init<<<(N_NODES + 255) / 256, 256, 0, stream>>>(dinv);
    k_deg_scatter<<<(N_EDGES + 255) / 256, 256, 0, stream>>>(dst, dinv);
    k_dinv<<<(N_NODES + 255) / 256, 256, 0, stream>>>(dinv);

    const int elem_blocks = (N_NODES * 64 + 255) / 256;
    const int node_blocks = (N_NODES + 3) / 4;      // 4 waves/block, 1 node/wave
    const int edge_blocks = (N_EDGES + 3) / 4;      // 4 edges/block

    const float* cur = x;
    for (int l = 0; l < 6; ++l) {
        if (l == 0)
            k_gemm<128><<<node_blocks, 256, 0, stream>>>(cur, W[l], h);
        else
            k_gemm<64><<<node_blocks, 256, 0, stream>>>(cur, W[l], h);
        k_selfloop<<<elem_blocks, 256, 0, stream>>>(h, dinv, agg);
        k_edge_scatter<<<edge_blocks, 256, 0, stream>>>(src, dst, dinv, h, agg);
        k_bias_relu<<<elem_blocks, 256, 0, stream>>>(agg, b[l]);
        cur = agg;
    }
    k_logsoftmax<<<node_blocks, 256, 0, stream>>>(agg, out);
}

// Round 3
// 1155.066 us; speedup vs baseline: 2.4120x; 2.4120x over previous
//
#include <hip/hip_runtime.h>
#include <math.h>

#define N_NODES 100000
#define N_EDGES 1600000
#define SCAN_BLK 1024
#define NSCAN ((N_NODES + SCAN_BLK - 1) / SCAN_BLK)   // 98 blocks

// ---------------- CSR build ----------------

__global__ void k_zero_i(int* __restrict__ p, int n) {
    int i = blockIdx.x * blockDim.x + threadIdx.x;
    if (i < n) p[i] = 0;
}

__global__ void k_count(const int* __restrict__ dst, int* __restrict__ deg) {
    int e = blockIdx.x * blockDim.x + threadIdx.x;
    if (e < N_EDGES) atomicAdd(&deg[dst[e]], 1);
}

__global__ void k_dinv(const int* __restrict__ deg, float* __restrict__ dinv) {
    int i = blockIdx.x * blockDim.x + threadIdx.x;
    if (i < N_NODES) dinv[i] = rsqrtf((float)(deg[i] + 1));  // +1 self-loop
}

// exclusive scan of deg -> rowptr, 3 passes
__global__ void k_scan1(const int* __restrict__ deg, int* __restrict__ rowptr,
                        int* __restrict__ sums) {
    __shared__ int s[SCAN_BLK];
    int t = threadIdx.x;
    int g = blockIdx.x * SCAN_BLK + t;
    int v = (g < N_NODES) ? deg[g] : 0;
    s[t] = v;
    __syncthreads();
    for (int off = 1; off < SCAN_BLK; off <<= 1) {
        int a = (t >= off) ? s[t - off] : 0;
        __syncthreads();
        s[t] += a;
        __syncthreads();
    }
    if (g < N_NODES) rowptr[g] = s[t] - v;           // exclusive
    if (t == SCAN_BLK - 1) sums[blockIdx.x] = s[t];  // block total
}

__global__ void k_scan2(int* __restrict__ sums) {
    __shared__ int s[128];
    int t = threadIdx.x;
    int v = (t < NSCAN) ? sums[t] : 0;
    s[t] = v;
    __syncthreads();
    for (int off = 1; off < 128; off <<= 1) {
        int a = (t >= off) ? s[t - off] : 0;
        __syncthreads();
        s[t] += a;
        __syncthreads();
    }
    if (t < NSCAN) sums[t] = s[t] - v;               // exclusive block offsets
}

__global__ void k_scan3(int* __restrict__ rowptr, const int* __restrict__ sums,
                        int* __restrict__ cursor) {
    int g = blockIdx.x * blockDim.x + threadIdx.x;
    if (g < N_NODES) {
        int r = rowptr[g] + sums[g / SCAN_BLK];
        rowptr[g] = r;
        cursor[g] = r;
    }
    if (g == 0) rowptr[N_NODES] = N_EDGES;
}

__global__ void k_fill(const int* __restrict__ src, const int* __restrict__ dst,
                       int* __restrict__ cursor, int* __restrict__ colv) {
    int e = blockIdx.x * blockDim.x + threadIdx.x;
    if (e >= N_EDGES) return;
    int pos = atomicAdd(&cursor[dst[e]], 1);
    colv[pos] = src[e];
}

// ---------------- dense GEMM: h' = (in @ W) * dinv[node] ----------------
// 4 waves/block, one node row per wave, lane = output column. W in LDS.

template<int DIN>
__global__ void k_gemm(const float* __restrict__ in, const float* __restrict__ W,
                       const float* __restrict__ dinv, float* __restrict__ h) {
    __shared__ float sW[DIN * 64];
    int tid = threadIdx.x;
    for (int k = tid; k < DIN * 64; k += 256) sW[k] = W[k];
    __syncthreads();

    int node = blockIdx.x * 4 + (tid >> 6);
    int col  = tid & 63;
    if (node >= N_NODES) return;

    const float4* __restrict__ row4 = (const float4*)(in + (size_t)node * DIN);
    float acc = 0.0f;
#pragma unroll
    for (int k4 = 0; k4 < DIN / 4; ++k4) {
        float4 rv = row4[k4];
        acc = fmaf(rv.x, sW[(k4 * 4 + 0) * 64 + col], acc);
        acc = fmaf(rv.y, sW[(k4 * 4 + 1) * 64 + col], acc);
        acc = fmaf(rv.z, sW[(k4 * 4 + 2) * 64 + col], acc);
        acc = fmaf(rv.w, sW[(k4 * 4 + 3) * 64 + col], acc);
    }
    h[((size_t)node << 6) + col] = acc * dinv[node];
}

// ---------------- fused aggregate ----------------
// out[d] = relu( dinv[d] * (sum_{s in N(d)} h'[s] + h'[d]) + bias )
// (+ log-softmax if LAST). One wave per node; 4 quarter-waves each gather a
// different edge's 256B row as 16 lanes x float4, cross-quarter shfl reduce.

template<int LAST>
__global__ void k_aggregate(const int* __restrict__ rowptr, const int* __restrict__ colv,
                            const float* __restrict__ h, const float* __restrict__ dinv,
                            const float* __restrict__ bias, float* __restrict__ outp) {
    int node = blockIdx.x * (blockDim.x >> 6) + (threadIdx.x >> 6);
    if (node >= N_NODES) return;
    int lane = threadIdx.x & 63;
    int q  = lane >> 4;    // quarter-wave 0..3 (edge slot)
    int ql = lane & 15;    // lane within quarter (column/4)

    int beg = rowptr[node], end = rowptr[node + 1];

    float4 acc = make_float4(0.f, 0.f, 0.f, 0.f);
    for (int k = beg + q; k < end; k += 4) {
        int s = colv[k];
        float4 hv = *((const float4*)(h + ((size_t)s << 6)) + ql);
        acc.x += hv.x; acc.y += hv.y; acc.z += hv.z; acc.w += hv.w;
    }
    // reduce the 4 quarter-waves (lanes ql, ql+16, ql+32, ql+48)
#pragma unroll
    for (int off = 16; off <= 32; off <<= 1) {
        acc.x += __shfl_xor(acc.x, off);
        acc.y += __shfl_xor(acc.y, off);
        acc.z += __shfl_xor(acc.z, off);
        acc.w += __shfl_xor(acc.w, off);
    }
    // self-loop + normalize + bias + relu (all quarters hold identical values)
    float4 hv = *((const float4*)(h + ((size_t)node << 6)) + ql);
    float dn = dinv[node];
    float4 bv = ((const float4*)bias)[ql];
    float4 r;
    r.x = fmaxf(fmaf(acc.x + hv.x, dn, bv.x), 0.f);
    r.y = fmaxf(fmaf(acc.y + hv.y, dn, bv.y), 0.f);
    r.z = fmaxf(fmaf(acc.z + hv.z, dn, bv.z), 0.f);
    r.w = fmaxf(fmaf(acc.w + hv.w, dn, bv.w), 0.f);

    if (LAST) {
        // log-softmax over the 64 columns (quarters redundant; reduce within 16)
        float m = fmaxf(fmaxf(r.x, r.y), fmaxf(r.z, r.w));
#pragma unroll
        for (int off = 1; off <= 8; off <<= 1) m = fmaxf(m, __shfl_xor(m, off));
        float ssum = expf(r.x - m) + expf(r.y - m) + expf(r.z - m) + expf(r.w - m);
#pragma unroll
        for (int off = 1; off <= 8; off <<= 1) ssum += __shfl_xor(ssum, off);
        float lse = m + logf(ssum);
        r.x -= lse; r.y -= lse; r.z -= lse; r.w -= lse;
    }
    if (q == 0) *((float4*)(outp + ((size_t)node << 6)) + ql) = r;
}

// ---------------- launch ----------------

extern "C" void kernel_launch(void* const* d_in, const int* in_sizes, int n_in,
                              void* d_out, int out_size, void* d_ws, size_t ws_size,
                              hipStream_t stream) {
    const float* x = (const float*)d_in[0];
    const int* ei  = (const int*)d_in[1];   // harness delivers integers as int32
    const int* src = ei;
    const int* dst = ei + N_EDGES;

    const float* W[6];
    const float* b[6];
    for (int i = 0; i < 6; ++i) {
        W[i] = (const float*)d_in[2 + 2 * i];
        b[i] = (const float*)d_in[3 + 2 * i];
    }
    float* out = (float*)d_out;

    // workspace layout
    char* p = (char*)d_ws;
    int*   deg    = (int*)p;              p += (size_t)N_NODES * 4;       // also reused as cursor
    int*   rowptr = (int*)p;              p += (size_t)(N_NODES + 1) * 4;
    int*   sums   = (int*)p;              p += 128 * 4;
    float* dinv   = (float*)p;            p += (size_t)N_NODES * 4;
    int*   colv   = (int*)p;              p += (size_t)N_EDGES * 4;
    float* h      = (float*)p;            // N_NODES*64 floats
    int*   cursor = deg;                  // deg dead after k_scan1/k_dinv

    const int nb_node = (N_NODES + 255) / 256;
    const int nb_edge = (N_EDGES + 255) / 256;
    const int nb_wave = (N_NODES + 3) / 4;   // 4 waves/block, 1 node/wave

    // CSR build (every call; deterministic work)
    k_zero_i<<<nb_node, 256, 0, stream>>>(deg, N_NODES);
    k_count<<<nb_edge, 256, 0, stream>>>(dst, deg);
    k_dinv<<<nb_node, 256, 0, stream>>>(deg, dinv);
    k_scan1<<<NSCAN, SCAN_BLK, 0, stream>>>(deg, rowptr, sums);
    k_scan2<<<1, 128, 0, stream>>>(sums);
    k_scan3<<<nb_node, 256, 0, stream>>>(rowptr, sums, cursor);
    k_fill<<<nb_edge, 256, 0, stream>>>(src, dst, cursor, colv);

    // 6 GCN layers; cur alternates: gemm(cur -> h), aggregate(h -> d_out)
    const float* cur = x;
    for (int l = 0; l < 6; ++l) {
        if (l == 0)
            k_gemm<128><<<nb_wave, 256, 0, stream>>>(cur, W[l], dinv, h);
        else
            k_gemm<64><<<nb_wave, 256, 0, stream>>>(cur, W[l], dinv, h);
        if (l == 5)
            k_aggregate<1><<<nb_wave, 256, 0, stream>>>(rowptr, colv, h, dinv, b[l], out);
        else
            k_aggregate<0><<<nb_wave, 256, 0, stream>>>(rowptr, colv, h, dinv, b[l], out);
        cur = out;
    }
}

// Round 4
// 816.050 us; speedup vs baseline: 3.4141x; 1.4154x over previous
//
#include <hip/hip_runtime.h>
#include <math.h>

#define N_NODES 100000
#define N_EDGES 1600000
#define SCAN_BLK 1024
#define NSCAN ((N_NODES + SCAN_BLK - 1) / SCAN_BLK)   // 98 blocks

// ---------------- CSR build ----------------

__global__ void k_zero_i(int* __restrict__ p, int n) {
    int i = blockIdx.x * blockDim.x + threadIdx.x;
    if (i < n) p[i] = 0;
}

__global__ void k_count(const int* __restrict__ dst, int* __restrict__ deg) {
    int e = blockIdx.x * blockDim.x + threadIdx.x;
    if (e < N_EDGES) atomicAdd(&deg[dst[e]], 1);
}

__global__ void k_dinv(const int* __restrict__ deg, float* __restrict__ dinv) {
    int i = blockIdx.x * blockDim.x + threadIdx.x;
    if (i < N_NODES) dinv[i] = rsqrtf((float)(deg[i] + 1));  // +1 self-loop
}

// exclusive scan of deg -> rowptr, 3 passes
__global__ void k_scan1(const int* __restrict__ deg, int* __restrict__ rowptr,
                        int* __restrict__ sums) {
    __shared__ int s[SCAN_BLK];
    int t = threadIdx.x;
    int g = blockIdx.x * SCAN_BLK + t;
    int v = (g < N_NODES) ? deg[g] : 0;
    s[t] = v;
    __syncthreads();
    for (int off = 1; off < SCAN_BLK; off <<= 1) {
        int a = (t >= off) ? s[t - off] : 0;
        __syncthreads();
        s[t] += a;
        __syncthreads();
    }
    if (g < N_NODES) rowptr[g] = s[t] - v;           // exclusive
    if (t == SCAN_BLK - 1) sums[blockIdx.x] = s[t];  // block total
}

__global__ void k_scan2(int* __restrict__ sums) {
    __shared__ int s[128];
    int t = threadIdx.x;
    int v = (t < NSCAN) ? sums[t] : 0;
    s[t] = v;
    __syncthreads();
    for (int off = 1; off < 128; off <<= 1) {
        int a = (t >= off) ? s[t - off] : 0;
        __syncthreads();
        s[t] += a;
        __syncthreads();
    }
    if (t < NSCAN) sums[t] = s[t] - v;               // exclusive block offsets
}

__global__ void k_scan3(int* __restrict__ rowptr, const int* __restrict__ sums,
                        int* __restrict__ cursor) {
    int g = blockIdx.x * blockDim.x + threadIdx.x;
    if (g < N_NODES) {
        int r = rowptr[g] + sums[g / SCAN_BLK];
        rowptr[g] = r;
        cursor[g] = r;
    }
    if (g == 0) rowptr[N_NODES] = N_EDGES;
}

__global__ void k_fill(const int* __restrict__ src, const int* __restrict__ dst,
                       int* __restrict__ cursor, int* __restrict__ colv) {
    int e = blockIdx.x * blockDim.x + threadIdx.x;
    if (e >= N_EDGES) return;
    int pos = atomicAdd(&cursor[dst[e]], 1);
    colv[pos] = src[e];
}

// ---------------- tiled GEMM: h' = (in @ W) * dinv[node] ----------------
// Block 256 threads = 64-node x 64-col tile; X-tile + W-chunk in LDS (rows
// padded to 68 floats -> <=2-way bank aliasing, free). Each thread owns a
// 4x4 register tile: per k, 4 broadcast ds_read_b32 + 1 ds_read_b128 + 16
// independent fma. DIN=128 runs two K-chunks through the same LDS.

template<int DIN>
__global__ __launch_bounds__(256) void k_gemm(const float* __restrict__ in,
                                              const float* __restrict__ W,
                                              const float* __restrict__ dinv,
                                              float* __restrict__ h) {
    __shared__ float sX[64 * 68];
    __shared__ float sW[64 * 68];
    int tid  = threadIdx.x;
    int lane = tid & 63, wave = tid >> 6;
    int node0 = blockIdx.x * 64;
    int r_base = wave * 16 + 4 * (lane >> 4);   // tile-local row of my 4 rows
    int c_base = 4 * (lane & 15);               // col of my 4 cols

    float acc[4][4] = {};

#pragma unroll
    for (int kc = 0; kc < DIN / 64; ++kc) {
        // stage X chunk (64 rows x 64 k) and W chunk (64 k x 64 cols)
#pragma unroll
        for (int i = 0; i < 4; ++i) {
            int idx = tid + i * 256;          // 0..1023
            int row = idx >> 4;
            int j4  = (idx & 15) * 4;
            int nr  = node0 + row; if (nr >= N_NODES) nr = N_NODES - 1;
            *(float4*)(sX + row * 68 + j4) =
                *(const float4*)(in + (size_t)nr * DIN + kc * 64 + j4);
            int k  = idx >> 4;
            int c4 = (idx & 15) * 4;
            *(float4*)(sW + k * 68 + c4) =
                *(const float4*)(W + (size_t)(kc * 64 + k) * 64 + c4);
        }
        __syncthreads();

#pragma unroll 16
        for (int k = 0; k < 64; ++k) {
            float4 wv = *(const float4*)(sW + k * 68 + c_base);
            float x0 = sX[(r_base + 0) * 68 + k];
            float x1 = sX[(r_base + 1) * 68 + k];
            float x2 = sX[(r_base + 2) * 68 + k];
            float x3 = sX[(r_base + 3) * 68 + k];
            acc[0][0] = fmaf(x0, wv.x, acc[0][0]); acc[0][1] = fmaf(x0, wv.y, acc[0][1]);
            acc[0][2] = fmaf(x0, wv.z, acc[0][2]); acc[0][3] = fmaf(x0, wv.w, acc[0][3]);
            acc[1][0] = fmaf(x1, wv.x, acc[1][0]); acc[1][1] = fmaf(x1, wv.y, acc[1][1]);
            acc[1][2] = fmaf(x1, wv.z, acc[1][2]); acc[1][3] = fmaf(x1, wv.w, acc[1][3]);
            acc[2][0] = fmaf(x2, wv.x, acc[2][0]); acc[2][1] = fmaf(x2, wv.y, acc[2][1]);
            acc[2][2] = fmaf(x2, wv.z, acc[2][2]); acc[2][3] = fmaf(x2, wv.w, acc[2][3]);
            acc[3][0] = fmaf(x3, wv.x, acc[3][0]); acc[3][1] = fmaf(x3, wv.y, acc[3][1]);
            acc[3][2] = fmaf(x3, wv.z, acc[3][2]); acc[3][3] = fmaf(x3, wv.w, acc[3][3]);
        }
        __syncthreads();
    }

#pragma unroll
    for (int i = 0; i < 4; ++i) {
        int r = node0 + r_base + i;
        if (r < N_NODES) {
            float dn = dinv[r];
            float4 o;
            o.x = acc[i][0] * dn; o.y = acc[i][1] * dn;
            o.z = acc[i][2] * dn; o.w = acc[i][3] * dn;
            *(float4*)(h + ((size_t)r << 6) + c_base) = o;
        }
    }
}

// ---------------- fused aggregate ----------------
// out[d] = relu( dinv[d] * (sum_{s in N(d)} h'[s] + h'[d]) + bias )
// (+ log-softmax if LAST). One wave per node; 4 quarter-waves each gather a
// different edge's 256B row as 16 lanes x float4, cross-quarter shfl reduce.

template<int LAST>
__global__ void k_aggregate(const int* __restrict__ rowptr, const int* __restrict__ colv,
                            const float* __restrict__ h, const float* __restrict__ dinv,
                            const float* __restrict__ bias, float* __restrict__ outp) {
    int node = blockIdx.x * (blockDim.x >> 6) + (threadIdx.x >> 6);
    if (node >= N_NODES) return;
    int lane = threadIdx.x & 63;
    int q  = lane >> 4;    // quarter-wave 0..3 (edge slot)
    int ql = lane & 15;    // lane within quarter (column/4)

    int beg = rowptr[node], end = rowptr[node + 1];

    float4 acc = make_float4(0.f, 0.f, 0.f, 0.f);
    for (int k = beg + q; k < end; k += 4) {
        int s = colv[k];
        float4 hv = *((const float4*)(h + ((size_t)s << 6)) + ql);
        acc.x += hv.x; acc.y += hv.y; acc.z += hv.z; acc.w += hv.w;
    }
    // reduce the 4 quarter-waves (lanes ql, ql+16, ql+32, ql+48)
#pragma unroll
    for (int off = 16; off <= 32; off <<= 1) {
        acc.x += __shfl_xor(acc.x, off);
        acc.y += __shfl_xor(acc.y, off);
        acc.z += __shfl_xor(acc.z, off);
        acc.w += __shfl_xor(acc.w, off);
    }
    // self-loop + normalize + bias + relu (all quarters hold identical values)
    float4 hv = *((const float4*)(h + ((size_t)node << 6)) + ql);
    float dn = dinv[node];
    float4 bv = ((const float4*)bias)[ql];
    float4 r;
    r.x = fmaxf(fmaf(acc.x + hv.x, dn, bv.x), 0.f);
    r.y = fmaxf(fmaf(acc.y + hv.y, dn, bv.y), 0.f);
    r.z = fmaxf(fmaf(acc.z + hv.z, dn, bv.z), 0.f);
    r.w = fmaxf(fmaf(acc.w + hv.w, dn, bv.w), 0.f);

    if (LAST) {
        // log-softmax over the 64 columns (quarters redundant; reduce within 16)
        float m = fmaxf(fmaxf(r.x, r.y), fmaxf(r.z, r.w));
#pragma unroll
        for (int off = 1; off <= 8; off <<= 1) m = fmaxf(m, __shfl_xor(m, off));
        float ssum = expf(r.x - m) + expf(r.y - m) + expf(r.z - m) + expf(r.w - m);
#pragma unroll
        for (int off = 1; off <= 8; off <<= 1) ssum += __shfl_xor(ssum, off);
        float lse = m + logf(ssum);
        r.x -= lse; r.y -= lse; r.z -= lse; r.w -= lse;
    }
    if (q == 0) *((float4*)(outp + ((size_t)node << 6)) + ql) = r;
}

// ---------------- launch ----------------

extern "C" void kernel_launch(void* const* d_in, const int* in_sizes, int n_in,
                              void* d_out, int out_size, void* d_ws, size_t ws_size,
                              hipStream_t stream) {
    const float* x = (const float*)d_in[0];
    const int* ei  = (const int*)d_in[1];   // harness delivers integers as int32
    const int* src = ei;
    const int* dst = ei + N_EDGES;

    const float* W[6];
    const float* b[6];
    for (int i = 0; i < 6; ++i) {
        W[i] = (const float*)d_in[2 + 2 * i];
        b[i] = (const float*)d_in[3 + 2 * i];
    }
    float* out = (float*)d_out;

    // workspace layout
    char* p = (char*)d_ws;
    int*   deg    = (int*)p;              p += (size_t)N_NODES * 4;       // reused as cursor
    int*   rowptr = (int*)p;              p += (size_t)(N_NODES + 1) * 4;
    int*   sums   = (int*)p;              p += 128 * 4;
    float* dinv   = (float*)p;            p += (size_t)N_NODES * 4;
    int*   colv   = (int*)p;              p += (size_t)N_EDGES * 4;
    float* h      = (float*)p;            // N_NODES*64 floats
    int*   cursor = deg;                  // deg dead after k_scan1/k_dinv

    const int nb_node = (N_NODES + 255) / 256;
    const int nb_edge = (N_EDGES + 255) / 256;
    const int nb_wave = (N_NODES + 3) / 4;      // aggregate: 1 node/wave
    const int nb_tile = (N_NODES + 63) / 64;    // gemm: 64 nodes/block

    // CSR build (every call; deterministic work)
    k_zero_i<<<nb_node, 256, 0, stream>>>(deg, N_NODES);
    k_count<<<nb_edge, 256, 0, stream>>>(dst, deg);
    k_dinv<<<nb_node, 256, 0, stream>>>(deg, dinv);
    k_scan1<<<NSCAN, SCAN_BLK, 0, stream>>>(deg, rowptr, sums);
    k_scan2<<<1, 128, 0, stream>>>(sums);
    k_scan3<<<nb_node, 256, 0, stream>>>(rowptr, sums, cursor);
    k_fill<<<nb_edge, 256, 0, stream>>>(src, dst, cursor, colv);

    // 6 GCN layers; gemm(cur -> h), aggregate(h -> d_out)
    const float* cur = x;
    for (int l = 0; l < 6; ++l) {
        if (l == 0)
            k_gemm<128><<<nb_tile, 256, 0, stream>>>(cur, W[l], dinv, h);
        else
            k_gemm<64><<<nb_tile, 256, 0, stream>>>(cur, W[l], dinv, h);
        if (l == 5)
            k_aggregate<1><<<nb_wave, 256, 0, stream>>>(rowptr, colv, h, dinv, b[l], out);
        else
            k_aggregate<0><<<nb_wave, 256, 0, stream>>>(rowptr, colv, h, dinv, b[l], out);
        cur = out;
    }
}